// Round 1
// 1294.776 us; speedup vs baseline: 1.0652x; 1.0652x over previous
//
#include <hip/hip_runtime.h>
#include <cstdio>

#define M_DIM 32768   // B*S = 4*8192
#define H_DIM 1024
#define I_DIM 4096

typedef __bf16 bf16x8 __attribute__((ext_vector_type(8)));
typedef float  f32x4  __attribute__((ext_vector_type(4)));

__device__ __forceinline__ unsigned short f2bf(float f) {
    unsigned int u = __float_as_uint(f);
    u += 0x7FFFu + ((u >> 16) & 1u);   // RNE
    return (unsigned short)(u >> 16);
}

__device__ __forceinline__ void async_cp16(const unsigned short* g, unsigned short* l) {
    __builtin_amdgcn_global_load_lds(
        (const __attribute__((address_space(1))) void*)g,
        (__attribute__((address_space(3))) void*)l, 16, 0, 0);
}

// src [R][C] f32 -> dst [C][R] bf16
__global__ __launch_bounds__(256) void transpose_cast_bf16(
    const float* __restrict__ src, unsigned short* __restrict__ dst, int R, int C)
{
    __shared__ float tile[32][33];
    int c0 = blockIdx.x * 32;
    int r0 = blockIdx.y * 32;
    int tx = threadIdx.x;   // 0..31
    int ty = threadIdx.y;   // 0..7
#pragma unroll
    for (int i = 0; i < 32; i += 8)
        tile[ty + i][tx] = src[(size_t)(r0 + ty + i) * C + (c0 + tx)];
    __syncthreads();
#pragma unroll
    for (int i = 0; i < 32; i += 8)
        dst[(size_t)(c0 + ty + i) * R + (r0 + tx)] = f2bf(tile[tx][ty + i]);
}

// residual_add = input + bias + residual ; x = LN(residual_add)*gamma+beta -> bf16
__global__ __launch_bounds__(256) void fused_addln(
    const float* __restrict__ inp, const float* __restrict__ resid,
    const float* __restrict__ bias, const float* __restrict__ gamma,
    const float* __restrict__ beta, unsigned short* __restrict__ xout)
{
    const int row = blockIdx.x;
    const int t = threadIdx.x;                       // 256 threads, H=1024 -> 1 float4 each
    const float4 v = ((const float4*)(inp   + (size_t)row * H_DIM))[t];
    const float4 r = ((const float4*)(resid + (size_t)row * H_DIM))[t];
    const float4 b = ((const float4*)bias)[t];
    float4 x;
    x.x = v.x + b.x + r.x;  x.y = v.y + b.y + r.y;
    x.z = v.z + b.z + r.z;  x.w = v.w + b.w + r.w;
    float s  = x.x + x.y + x.z + x.w;
    float s2 = x.x*x.x + x.y*x.y + x.z*x.z + x.w*x.w;
#pragma unroll
    for (int off = 32; off > 0; off >>= 1) {
        s  += __shfl_down(s,  off, 64);
        s2 += __shfl_down(s2, off, 64);
    }
    __shared__ float red[8];
    const int wid = t >> 6, lane = t & 63;
    if (lane == 0) { red[wid] = s; red[4 + wid] = s2; }
    __syncthreads();
    s  = red[0] + red[1] + red[2] + red[3];
    s2 = red[4] + red[5] + red[6] + red[7];
    const float mu   = s * (1.0f / H_DIM);
    const float var  = s2 * (1.0f / H_DIM) - mu * mu;
    const float rstd = rsqrtf(var + 1e-5f);
    const float4 g  = ((const float4*)gamma)[t];
    const float4 be = ((const float4*)beta)[t];
    ushort4 o;
    o.x = f2bf((x.x - mu) * rstd * g.x + be.x);
    o.y = f2bf((x.y - mu) * rstd * g.y + be.y);
    o.z = f2bf((x.z - mu) * rstd * g.z + be.z);
    o.w = f2bf((x.w - mu) * rstd * g.w + be.w);
    ((ushort4*)(xout + (size_t)row * H_DIM))[t] = o;
}

// =====================================================================
// 256x256 8-phase GEMM (T2+T3+T4+T5 stack), C[M][N] = A[M][K] * BT[N][K]^T
//   512 thr = 8 waves (2 wm x 4 wn); per-wave 128x64 out = acc[8][4] f32x4
//   BK=64; LDS = 2 parity x 2 K-half slots per operand, slot = 256rows x 32el
//         = 16KB; total 128 KiB.
//   Per K-tile: 4 phases (kk,qm). Per phase: ds_read frags | stage one slot
//   (2x global_load_lds_dwordx4) | barrier | lgkmcnt(0) | setprio(1) |
//   16x mfma_16x16x32_bf16 | setprio(0) | barrier.
//   Counted vmcnt(8) at phases 2&4 of every group (4 slot-pairs in flight,
//   never drained to 0 in the loop).
//   Slot-rotation (group = tile t, parity p):
//     P1 stage A[p^1][k1] <- (t+1).k1   (slot dead since prev group P4)
//     P2 stage B[p^1][k1] <- (t+1).k1
//     P3 stage A[p][k0]   <- (t+2).k0   (slot dead after this group's P2)
//     P4 stage B[p][k0]   <- (t+2).k0
//   Ledger-checked: every slot lands >=1 vmcnt(8)+barrier before first read,
//   and is re-staged only after a barrier that postdates its last read.
//   LDS swizzle: chunk ^= (row>>1)&3 (16B chunks) applied on the GLOBAL
//   source address (global_load_lds dest must stay linear) and on ds_read.
// =====================================================================

#define BAR()   __builtin_amdgcn_s_barrier()
#define LGKM0() asm volatile("s_waitcnt lgkmcnt(0)" ::: "memory")
#define VM8()   asm volatile("s_waitcnt vmcnt(8)" ::: "memory")
#define PRIO1() __builtin_amdgcn_s_setprio(1)
#define PRIO0() __builtin_amdgcn_s_setprio(0)

#define LOADA(PAR, KK, QM)                                                 \
    { const unsigned short* a_ = &As[(PAR)][(KK)][aoff + (QM) * 2048];     \
      af[0] = *(const bf16x8*)&a_[0];                                      \
      af[1] = *(const bf16x8*)&a_[512];                                    \
      af[2] = *(const bf16x8*)&a_[1024];                                   \
      af[3] = *(const bf16x8*)&a_[1536]; }

#define LOADB(PAR, KK)                                                     \
    { const unsigned short* b_ = &Bs[(PAR)][(KK)][boff];                   \
      bfv[0] = *(const bf16x8*)&b_[0];                                     \
      bfv[1] = *(const bf16x8*)&b_[512];                                   \
      bfv[2] = *(const bf16x8*)&b_[1024];                                  \
      bfv[3] = *(const bf16x8*)&b_[1536]; }

#define MFMA16(QM)                                                         \
    _Pragma("unroll") for (int j_ = 0; j_ < 4; j_++)                       \
      _Pragma("unroll") for (int n_ = 0; n_ < 4; n_++)                     \
        acc[(QM) * 4 + j_][n_] = __builtin_amdgcn_mfma_f32_16x16x32_bf16(  \
            af[j_], bfv[n_], acc[(QM) * 4 + j_][n_], 0, 0, 0);

#define STAGE_A(PAR, KK, KB)                                               \
    async_cp16(Ag0 + (KB), &As[(PAR)][(KK)][lds0]);                        \
    async_cp16(Ag1 + (KB), &As[(PAR)][(KK)][lds0 + 4096]);

#define STAGE_B(PAR, KK, KB)                                               \
    async_cp16(Bg0 + (KB), &Bs[(PAR)][(KK)][lds0]);                        \
    async_cp16(Bg1 + (KB), &Bs[(PAR)][(KK)][lds0 + 4096]);

#define GROUP(PAR, KA1, KB1, KA2, KB2)                                     \
    /* P1: kk=0 qm=0 */                                                    \
    LOADA(PAR, 0, 0) LOADB(PAR, 0)                                         \
    STAGE_A((PAR) ^ 1, 1, KA1)                                             \
    BAR(); LGKM0(); PRIO1(); MFMA16(0) PRIO0(); BAR();                     \
    /* P2: kk=0 qm=1 */                                                    \
    LOADA(PAR, 0, 1)                                                       \
    STAGE_B((PAR) ^ 1, 1, KB1)                                             \
    VM8();                                                                 \
    BAR(); LGKM0(); PRIO1(); MFMA16(1) PRIO0(); BAR();                     \
    /* P3: kk=1 qm=0 */                                                    \
    LOADA(PAR, 1, 0) LOADB(PAR, 1)                                         \
    STAGE_A(PAR, 0, KA2)                                                   \
    BAR(); LGKM0(); PRIO1(); MFMA16(0) PRIO0(); BAR();                     \
    /* P4: kk=1 qm=1 */                                                    \
    LOADA(PAR, 1, 1)                                                       \
    STAGE_B(PAR, 0, KB2)                                                   \
    VM8();                                                                 \
    BAR(); LGKM0(); PRIO1(); MFMA16(1) PRIO0(); BAR();

// EPI==0: += nbias, tanh-GELU, store bf16.  EPI==1: += nbias+inp+resid+hbias, f32.
template <int EPI>
__global__ __launch_bounds__(512, 2) void gemm256(
    const unsigned short* __restrict__ A,
    const unsigned short* __restrict__ BT,
    unsigned short* __restrict__ outb,
    float* __restrict__ outf,
    const float* __restrict__ nbias,
    const float* __restrict__ inp,
    const float* __restrict__ resid,
    const float* __restrict__ hbias,
    int M, int N, int K)
{
    __shared__ unsigned short As[2][2][8192];   // [parity][khalf][256 rows x 32 el]
    __shared__ unsigned short Bs[2][2][8192];

    const int tid  = threadIdx.x;
    const int lane = tid & 63;
    const int wid  = tid >> 6;          // 0..7
    const int wm   = wid >> 2;          // 0..1
    const int wn   = wid & 3;           // 0..3
    const int fr   = lane & 15;
    const int fq   = lane >> 4;

    // ---- block swizzle: XCD-contiguous remap + 8-m-tile strips ----
    const int mt = M >> 8, nt = N >> 8;
    const int nblk = mt * nt;
    int lbid = blockIdx.x;
    if ((nblk & 7) == 0) {
        const int per = nblk >> 3;
        lbid = (lbid & 7) * per + (lbid >> 3);
    }
    const int strip_blocks = nt << 3;
    const int strip = lbid / strip_blocks;
    const int rem   = lbid - strip * strip_blocks;
    const int m0 = (strip * 8 + (rem & 7)) << 8;
    const int n0 = (rem >> 3) << 8;

    // ---- staging decode (fixed per thread) -------------------------------
    // physical 16B unit s = issue*512+tid; row = s>>2; phys chunk = s&3;
    // logical chunk it must hold = phys ^ ((row>>1)&3)  (involution swizzle)
    const int s1 = tid + 512;
    const int r0 = tid >> 2;
    const int r1 = s1 >> 2;
    const int c0 = ((tid & 3) ^ ((r0 >> 1) & 3)) << 3;   // element offset
    const int c1 = ((s1 & 3) ^ ((r1 >> 1) & 3)) << 3;
    const unsigned short* Ag0 = A  + (size_t)(m0 + r0) * K + c0;
    const unsigned short* Ag1 = A  + (size_t)(m0 + r1) * K + c1;
    const unsigned short* Bg0 = BT + (size_t)(n0 + r0) * K + c0;
    const unsigned short* Bg1 = BT + (size_t)(n0 + r1) * K + c1;
    const int lds0 = tid * 8;

    // ---- fragment read offsets (swizzled chunk) --------------------------
    const int ch   = (fq ^ ((fr >> 1) & 3)) << 3;
    const int aoff = (wm * 128 + fr) * 32 + ch;   // + (qm*4+j)*512
    const int boff = (wn * 64 + fr) * 32 + ch;    // + ni*512

    f32x4 acc[8][4] = {};
    bf16x8 af[4], bfv[4];

    const int T = K >> 6;               // K-tiles (16 or 64; even)

    // ---- prologue: tile0.k0, tile0.k1, tile1.k0 --------------------------
    STAGE_A(0, 0, 0)  STAGE_B(0, 0, 0)
    STAGE_A(0, 1, 32) STAGE_B(0, 1, 32)
    const int k10 = (T > 1) ? 64 : 0;
    STAGE_A(1, 0, k10) STAGE_B(1, 0, k10)
    VM8();                              // oldest 4 loads (tile0.k0 A,B) landed
    BAR();

    for (int t = 0; t < T; t += 2) {
        const int a1 = (((t + 1 < T) ? t + 1 : T - 1) << 6) + 32;  // (t+1).k1
        const int a2 =  ((t + 2 < T) ? t + 2 : T - 1) << 6;        // (t+2).k0
        const int a3 = a2 + 32;                                    // (t+2).k1
        const int a4 =  ((t + 3 < T) ? t + 3 : T - 1) << 6;        // (t+3).k0
        GROUP(0, a1, a1, a2, a2)
        GROUP(1, a3, a3, a4, a4)
    }

    asm volatile("s_waitcnt vmcnt(0)" ::: "memory");  // drain tail garbage loads

    // ---- epilogue: C/D layout col=lane&15, row=(lane>>4)*4+reg -----------
    const int colb = n0 + wn * 64;
    const int rowb = m0 + wm * 128;
#pragma unroll
    for (int ni = 0; ni < 4; ni++) {
        const int col = colb + ni * 16 + fr;
        const float bn = nbias[col];
#pragma unroll
        for (int mi = 0; mi < 8; mi++) {
            const int row0 = rowb + mi * 16 + fq * 4;
#pragma unroll
            for (int rg = 0; rg < 4; rg++) {
                const size_t idx = (size_t)(row0 + rg) * N + col;
                float v = acc[mi][ni][rg] + bn;
                if (EPI == 0) {
                    // jax.nn.gelu approximate=True
                    float u  = 0.7978845608028654f * (v + 0.044715f * v * v * v);
                    float e  = __expf(2.0f * u);
                    float th = 1.0f - 2.0f / (e + 1.0f);
                    outb[idx] = f2bf(0.5f * v * (1.0f + th));
                } else {
                    outf[idx] = v + inp[idx] + resid[idx] + hbias[col];
                }
            }
        }
    }
}

extern "C" void kernel_launch(void* const* d_in, const int* in_sizes, int n_in,
                              void* d_out, int out_size, void* d_ws, size_t ws_size,
                              hipStream_t stream) {
    const float* input    = (const float*)d_in[0];
    const float* residual = (const float*)d_in[1];
    // d_in[2] residual_norm: unused by the reference
    const float* bias     = (const float*)d_in[3];
    const float* attn_nw  = (const float*)d_in[4];
    const float* attn_nb  = (const float*)d_in[5];
    const float* inter_w  = (const float*)d_in[6];   // [H][I]
    const float* inter_b  = (const float*)d_in[7];   // [I]
    const float* output_w = (const float*)d_in[8];   // [I][H]
    const float* output_b = (const float*)d_in[9];   // [H]
    float* out = (float*)d_out;

    char* ws = (char*)d_ws;
    unsigned short* Xb  = (unsigned short*)ws;                                   // M*H bf16
    unsigned short* W1T = (unsigned short*)(ws + (size_t)M_DIM * H_DIM * 2);     // [I][H]
    unsigned short* W2T = W1T + (size_t)I_DIM * H_DIM;                           // [H][I]
    unsigned short* Hb  = W2T + (size_t)H_DIM * I_DIM;                           // M*I bf16
    const size_t need = (size_t)M_DIM * H_DIM * 2 + 2 * (size_t)I_DIM * H_DIM * 2
                      + (size_t)M_DIM * I_DIM * 2;
    if (ws_size < need)
        fprintf(stderr, "WARNING: ws_size %zu < needed %zu\n", ws_size, need);

    // W1 [H][I] -> W1T [I][H];  W2 [I][H] -> W2T [H][I]
    transpose_cast_bf16<<<dim3(I_DIM / 32, H_DIM / 32), dim3(32, 8), 0, stream>>>(
        inter_w, W1T, H_DIM, I_DIM);
    transpose_cast_bf16<<<dim3(H_DIM / 32, I_DIM / 32), dim3(32, 8), 0, stream>>>(
        output_w, W2T, I_DIM, H_DIM);

    fused_addln<<<M_DIM, 256, 0, stream>>>(input, residual, bias, attn_nw, attn_nb, Xb);

    gemm256<0><<<(M_DIM / 256) * (I_DIM / 256), 512, 0, stream>>>(
        Xb, W1T, Hb, nullptr, inter_b, nullptr, nullptr, nullptr, M_DIM, I_DIM, H_DIM);

    gemm256<1><<<(M_DIM / 256) * (H_DIM / 256), 512, 0, stream>>>(
        Hb, W2T, nullptr, out, output_b, input, residual, bias, M_DIM, H_DIM, I_DIM);
}

// Round 2
// 1071.207 us; speedup vs baseline: 1.2875x; 1.2087x over previous
//
#include <hip/hip_runtime.h>
#include <cstdio>

#define M_DIM 32768   // B*S = 4*8192
#define H_DIM 1024
#define I_DIM 4096

typedef __bf16 bf16x8 __attribute__((ext_vector_type(8)));
typedef float  f32x4  __attribute__((ext_vector_type(4)));

__device__ __forceinline__ unsigned short f2bf(float f) {
    unsigned int u = __float_as_uint(f);
    u += 0x7FFFu + ((u >> 16) & 1u);   // RNE
    return (unsigned short)(u >> 16);
}

__device__ __forceinline__ void async_cp16(const unsigned short* g, unsigned short* l) {
    __builtin_amdgcn_global_load_lds(
        (const __attribute__((address_space(1))) void*)g,
        (__attribute__((address_space(3))) void*)l, 16, 0, 0);
}

// src [R][C] f32 -> dst packed [R/32][C][32] bf16   (dst logical [C][R], K=R dim chunked)
__global__ __launch_bounds__(256) void transpose_cast_bf16(
    const float* __restrict__ src, unsigned short* __restrict__ dst, int R, int C)
{
    __shared__ float tile[32][33];
    int c0 = blockIdx.x * 32;
    int r0 = blockIdx.y * 32;
    int tx = threadIdx.x;   // 0..31
    int ty = threadIdx.y;   // 0..7
#pragma unroll
    for (int i = 0; i < 32; i += 8)
        tile[ty + i][tx] = src[(size_t)(r0 + ty + i) * C + (c0 + tx)];
    __syncthreads();
    // packed idx = (k>>5)*(C*32) + n*32 + (k&31), k=r0+tx, n=c0+ty+i
    const size_t kslab = (size_t)(r0 >> 5) * ((size_t)C * 32);
#pragma unroll
    for (int i = 0; i < 32; i += 8)
        dst[kslab + (size_t)(c0 + ty + i) * 32 + tx] = f2bf(tile[tx][ty + i]);
}

// residual_add = input + bias + residual ; x = LN(residual_add)*gamma+beta
// -> bf16, K-packed layout [H/32][M][32]
__global__ __launch_bounds__(256) void fused_addln(
    const float* __restrict__ inp, const float* __restrict__ resid,
    const float* __restrict__ bias, const float* __restrict__ gamma,
    const float* __restrict__ beta, unsigned short* __restrict__ xout)
{
    const int row = blockIdx.x;
    const int t = threadIdx.x;                       // 256 threads, H=1024 -> 1 float4 each
    const float4 v = ((const float4*)(inp   + (size_t)row * H_DIM))[t];
    const float4 r = ((const float4*)(resid + (size_t)row * H_DIM))[t];
    const float4 b = ((const float4*)bias)[t];
    float4 x;
    x.x = v.x + b.x + r.x;  x.y = v.y + b.y + r.y;
    x.z = v.z + b.z + r.z;  x.w = v.w + b.w + r.w;
    float s  = x.x + x.y + x.z + x.w;
    float s2 = x.x*x.x + x.y*x.y + x.z*x.z + x.w*x.w;
#pragma unroll
    for (int off = 32; off > 0; off >>= 1) {
        s  += __shfl_down(s,  off, 64);
        s2 += __shfl_down(s2, off, 64);
    }
    __shared__ float red[8];
    const int wid = t >> 6, lane = t & 63;
    if (lane == 0) { red[wid] = s; red[4 + wid] = s2; }
    __syncthreads();
    s  = red[0] + red[1] + red[2] + red[3];
    s2 = red[4] + red[5] + red[6] + red[7];
    const float mu   = s * (1.0f / H_DIM);
    const float var  = s2 * (1.0f / H_DIM) - mu * mu;
    const float rstd = rsqrtf(var + 1e-5f);
    const float4 g  = ((const float4*)gamma)[t];
    const float4 be = ((const float4*)beta)[t];
    ushort4 o;
    o.x = f2bf((x.x - mu) * rstd * g.x + be.x);
    o.y = f2bf((x.y - mu) * rstd * g.y + be.y);
    o.z = f2bf((x.z - mu) * rstd * g.z + be.z);
    o.w = f2bf((x.w - mu) * rstd * g.w + be.w);
    // packed: (h>>5)*(M*32) + row*32 + (h&31), h = 4t
    const size_t pidx = (size_t)(t >> 3) * ((size_t)M_DIM * 32)
                      + (size_t)row * 32 + ((4 * t) & 31);
    *(ushort4*)(xout + pidx) = o;
}

// =====================================================================
// 256x256 GEMM, 1024 thr = 16 waves (4M x 4N), per-wave 64x64 out.
//   BK=32, quad-buffered 16KB slots (LDS 128 KiB), ONE phase per K-tile:
//     stage tile t+3 (2x global_load_lds, 16KB each, contiguous K-packed)
//     8x ds_read_b128 (af[4], bfv[4])  |  setprio(1) 16 MFMA setprio(0)
//     s_waitcnt vmcnt(4)   <- counted: t+2,t+3 stay in flight, t+1 landed
//     s_barrier            <- after-barrier, whole slot t+1 valid for all waves
//   Ledger: stage->read distance ~3 phases (~3000 cyc) >> HBM 900 cyc.
//   Stage target (t+3)&3 = slot freed at end of phase t-1 (>=1 barrier before
//   issue -> no cross-wave write/read race). Tail stages clamp to T-1 into
//   dead slots (keeps vmcnt ledger uniform; garbage never read).
//   Operands K-packed [K/32][rows][32]: per-wave staging reads 1KB contiguous.
//   LDS swizzle: 16B chunk ^= (row>>1)&3, applied on global source (dest must
//   stay linear for global_load_lds) and on ds_read addresses. (0 conflicts
//   measured with this scheme in R1.)
// =====================================================================

#define BAR()   __builtin_amdgcn_s_barrier()
#define VM4()   asm volatile("s_waitcnt vmcnt(4)" ::: "memory")
#define PRIO1() __builtin_amdgcn_s_setprio(1)
#define PRIO0() __builtin_amdgcn_s_setprio(0)

// EPI==0: += nbias, tanh-GELU, store bf16 K-packed [N/32][M][32].
// EPI==1: += nbias + inp + resid + hbias, store f32 [M][N].
template <int EPI>
__global__ __launch_bounds__(1024) void gemm256(
    const unsigned short* __restrict__ A,    // packed [K/32][M][32]
    const unsigned short* __restrict__ BT,   // packed [K/32][N][32]
    unsigned short* __restrict__ outb,
    float* __restrict__ outf,
    const float* __restrict__ nbias,
    const float* __restrict__ inp,
    const float* __restrict__ resid,
    const float* __restrict__ hbias,
    int M, int N, int K)
{
    __shared__ unsigned short As[4 * 8192];   // 4 slots x 256 rows x 32 el
    __shared__ unsigned short Bs[4 * 8192];

    const int tid  = threadIdx.x;
    const int lane = tid & 63;
    const int wid  = tid >> 6;          // 0..15
    const int wm   = wid >> 2;          // 0..3
    const int wn   = wid & 3;           // 0..3
    const int fr   = lane & 15;
    const int fq   = lane >> 4;

    // ---- block swizzle: XCD-contiguous remap + 8-m-tile strips ----
    const int mt = M >> 8, nt = N >> 8;
    const int nblk = mt * nt;
    int lbid = blockIdx.x;
    if ((nblk & 7) == 0) {
        const int per = nblk >> 3;
        lbid = (lbid & 7) * per + (lbid >> 3);
    }
    const int strip_blocks = nt << 3;
    const int strip = lbid / strip_blocks;
    const int rem   = lbid - strip * strip_blocks;
    const int m0 = (strip * 8 + (rem & 7)) << 8;
    const int n0 = (rem >> 3) << 8;

    // ---- staging: per-lane source offset (chunk-XOR pre-swizzle) ---------
    // LDS unit u = tid: row=u>>2, phys chunk=u&3 must hold logical chunk
    // phys ^ ((row>>1)&3). Source stays within the row's 64B -> dense 1KB/wave.
    const int srow = tid >> 2;                         // 0..255
    const int csw  = (tid & 3) ^ ((srow >> 1) & 3);
    const unsigned short* Asrc = A  + (size_t)(m0 + srow) * 32 + csw * 8;
    const unsigned short* Bsrc = BT + (size_t)(n0 + srow) * 32 + csw * 8;
    const size_t slabA = (size_t)M * 32;               // elems per K-chunk slab
    const size_t slabB = (size_t)N * 32;
    const int ldst = wid * 512;                        // wave-uniform LDS dest

    // ---- fragment read offsets (swizzled chunk) --------------------------
    const int ch   = (fq ^ ((fr >> 1) & 3)) << 3;
    const int aoff = (wm * 64 + fr) * 32 + ch;         // + mi*512
    const int boff = (wn * 64 + fr) * 32 + ch;         // + ni*512

    f32x4 acc[4][4] = {};

    const int T = K >> 5;               // K-tiles (32 or 128; multiple of 4)

    // ---- prologue: tiles 0,1,2 -> slots 0,1,2 ----------------------------
    async_cp16(Asrc,              &As[0 * 8192 + ldst]);
    async_cp16(Bsrc,              &Bs[0 * 8192 + ldst]);
    async_cp16(Asrc + 1 * slabA,  &As[1 * 8192 + ldst]);
    async_cp16(Bsrc + 1 * slabB,  &Bs[1 * 8192 + ldst]);
    async_cp16(Asrc + 2 * slabA,  &As[2 * 8192 + ldst]);
    async_cp16(Bsrc + 2 * slabB,  &Bs[2 * 8192 + ldst]);
    VM4();                               // tile0 landed (t1,t2 in flight)
    BAR();

    for (int t = 0; t < T; t += 4) {
#pragma unroll
        for (int j = 0; j < 4; ++j) {
            const int SL = j;                      // (t+j)&3
            const int ST = (j + 3) & 3;            // slot freed last phase
            int ts = t + j + 3;                    // tile to stage (clamped)
            if (ts > T - 1) ts = T - 1;
            async_cp16(Asrc + (size_t)ts * slabA, &As[ST * 8192 + ldst]);
            async_cp16(Bsrc + (size_t)ts * slabB, &Bs[ST * 8192 + ldst]);

            bf16x8 af[4], bfv[4];
#pragma unroll
            for (int mi = 0; mi < 4; mi++)
                af[mi] = *(const bf16x8*)&As[SL * 8192 + aoff + mi * 512];
#pragma unroll
            for (int ni = 0; ni < 4; ni++)
                bfv[ni] = *(const bf16x8*)&Bs[SL * 8192 + boff + ni * 512];

            PRIO1();
#pragma unroll
            for (int ni = 0; ni < 4; ni++)
#pragma unroll
                for (int mi = 0; mi < 4; mi++)
                    acc[mi][ni] = __builtin_amdgcn_mfma_f32_16x16x32_bf16(
                        af[mi], bfv[ni], acc[mi][ni], 0, 0, 0);
            PRIO0();

            VM4();      // tile t+j+1 fully landed (per-wave) ...
            BAR();      // ... and for ALL waves after the barrier
        }
    }

    asm volatile("s_waitcnt vmcnt(0)" ::: "memory");  // drain tail stages

    // ---- epilogue: C/D layout col=lane&15, row=(lane>>4)*4+reg -----------
    const int colb = n0 + wn * 64;
    const int rowb = m0 + wm * 64;
#pragma unroll
    for (int ni = 0; ni < 4; ni++) {
        const int col = colb + ni * 16 + fr;
        const float bn = nbias[col];
#pragma unroll
        for (int mi = 0; mi < 4; mi++) {
            const int row0 = rowb + mi * 16 + fq * 4;
#pragma unroll
            for (int rg = 0; rg < 4; rg++) {
                const int row = row0 + rg;
                float v = acc[mi][ni][rg] + bn;
                if (EPI == 0) {
                    // jax.nn.gelu approximate=True
                    float u  = 0.7978845608028654f * (v + 0.044715f * v * v * v);
                    float e  = __expf(2.0f * u);
                    float th = 1.0f - 2.0f / (e + 1.0f);
                    // packed [N/32][M][32]
                    const size_t idx = (size_t)(col >> 5) * slabA
                                     + (size_t)row * 32 + (col & 31);
                    outb[idx] = f2bf(v * 0.5f * (1.0f + th));
                } else {
                    const size_t idx = (size_t)row * N + col;
                    outf[idx] = v + inp[idx] + resid[idx] + hbias[col];
                }
            }
        }
    }
}

extern "C" void kernel_launch(void* const* d_in, const int* in_sizes, int n_in,
                              void* d_out, int out_size, void* d_ws, size_t ws_size,
                              hipStream_t stream) {
    const float* input    = (const float*)d_in[0];
    const float* residual = (const float*)d_in[1];
    // d_in[2] residual_norm: unused by the reference
    const float* bias     = (const float*)d_in[3];
    const float* attn_nw  = (const float*)d_in[4];
    const float* attn_nb  = (const float*)d_in[5];
    const float* inter_w  = (const float*)d_in[6];   // [H][I]
    const float* inter_b  = (const float*)d_in[7];   // [I]
    const float* output_w = (const float*)d_in[8];   // [I][H]
    const float* output_b = (const float*)d_in[9];   // [H]
    float* out = (float*)d_out;

    char* ws = (char*)d_ws;
    unsigned short* Xb  = (unsigned short*)ws;                                   // packed [H/32][M][32]
    unsigned short* W1T = (unsigned short*)(ws + (size_t)M_DIM * H_DIM * 2);     // packed [H/32][I][32]
    unsigned short* W2T = W1T + (size_t)I_DIM * H_DIM;                           // packed [I/32][H][32]
    unsigned short* Hb  = W2T + (size_t)H_DIM * I_DIM;                           // packed [I/32][M][32]
    const size_t need = (size_t)M_DIM * H_DIM * 2 + 2 * (size_t)I_DIM * H_DIM * 2
                      + (size_t)M_DIM * I_DIM * 2;
    if (ws_size < need)
        fprintf(stderr, "WARNING: ws_size %zu < needed %zu\n", ws_size, need);

    // W1 [H][I] -> packed [H/32][I][32];  W2 [I][H] -> packed [I/32][H][32]
    transpose_cast_bf16<<<dim3(I_DIM / 32, H_DIM / 32), dim3(32, 8), 0, stream>>>(
        inter_w, W1T, H_DIM, I_DIM);
    transpose_cast_bf16<<<dim3(H_DIM / 32, I_DIM / 32), dim3(32, 8), 0, stream>>>(
        output_w, W2T, I_DIM, H_DIM);

    fused_addln<<<M_DIM, 256, 0, stream>>>(input, residual, bias, attn_nw, attn_nb, Xb);

    gemm256<0><<<(M_DIM / 256) * (I_DIM / 256), 1024, 0, stream>>>(
        Xb, W1T, Hb, nullptr, inter_b, nullptr, nullptr, nullptr, M_DIM, I_DIM, H_DIM);

    gemm256<1><<<(M_DIM / 256) * (H_DIM / 256), 1024, 0, stream>>>(
        Hb, W2T, nullptr, out, output_b, input, residual, bias, M_DIM, H_DIM, I_DIM);
}